// Round 6
// baseline (654.879 us; speedup 1.0000x reference)
//
#include <hip/hip_runtime.h>
#include <hip/hip_bf16.h>

typedef short bf16x8 __attribute__((ext_vector_type(8)));
typedef float f32x4 __attribute__((ext_vector_type(4)));

#define HID 256
#define IN_DIM 128
#define LDS_US 264      // LDS row stride in ushorts (=132 dwords; 132%32=4 -> conflict-free phases)
#define TPB 4           // tiles (of 64 edges) per block, software-pipelined

__device__ __forceinline__ float bf2f(unsigned short x) {
    union { unsigned int u; float f; } c; c.u = ((unsigned int)x) << 16; return c.f;
}
__device__ __forceinline__ unsigned short f2bf(float f) {
    union { float f; unsigned int u; } c; c.f = f;
    unsigned int u = c.u;
    u += 0x7FFFu + ((u >> 16) & 1u);   // RNE
    return (unsigned short)(u >> 16);
}
__device__ __forceinline__ unsigned int pack2(float lo, float hi) {
    return (unsigned int)f2bf(lo) | ((unsigned int)f2bf(hi) << 16);
}
__device__ __forceinline__ bool detect_bf16(const unsigned short* p, int strideElems) {
    const int lane = threadIdx.x & 63;
    unsigned int u = p[(size_t)2 * lane * strideElems];
    unsigned int e = (u >> 7) & 0xFFu;
    bool bad = ((u & 0x7FFFu) != 0u) && (e < 90u || e > 141u);
    return __ballot(bad) == 0ull;
}
__device__ __forceinline__ bool detect_idx64(const int* p) {
    const int lane = threadIdx.x & 63;
    int v = p[2 * (lane * 64) + 1];
    return __ballot(v != 0) == 0ull;
}

// ---- prep 1: fp32 tables -> bf16 tables in d_ws (streaming, HBM-bound) ----
extern "C" __global__ void cvt_tables_kernel(
    const float* __restrict__ uT, const float* __restrict__ iT,
    unsigned short* __restrict__ ub, unsigned short* __restrict__ ib,
    int nu8, int ni8)
{
    int g = blockIdx.x * 256 + threadIdx.x;
    if (g >= nu8 + ni8) return;
    const float* src; unsigned short* dst; int idx;
    if (g < nu8) { src = uT; dst = ub; idx = g; }
    else         { src = iT; dst = ib; idx = g - nu8; }
    const float4* s4 = reinterpret_cast<const float4*>(src) + (size_t)idx * 2;
    float4 a = s4[0], b = s4[1];
    uint4 o;
    o.x = pack2(a.x, a.y); o.y = pack2(a.z, a.w);
    o.z = pack2(b.x, b.y); o.w = pack2(b.z, b.w);
    reinterpret_cast<uint4*>(dst)[idx] = o;
}

// ---- prep 2: W1 -> bf16 B-fragment order (proven R5 code) ----
extern "C" __global__ void pack_w1_kernel(
    const void* __restrict__ W1c, const void* __restrict__ W1b,
    unsigned short* __restrict__ outp)
{
    const int t = blockIdx.y;
    const void* W1 = t ? W1b : W1c;
    const unsigned short* W1u = (const unsigned short*)W1;
    const float* W1f = (const float*)W1;
    const bool w1bf = detect_bf16(W1u, 512);
    const int tid = blockIdx.x * 256 + threadIdx.x;
    const int lane = tid & 63;
    const int nt = (tid >> 6) & 15;
    const int kt = tid >> 10;
    const int k0 = kt * 32 + (lane >> 4) * 8;
    const int n  = nt * 16 + (lane & 15);
    unsigned short vals[8];
#pragma unroll
    for (int j = 0; j < 8; ++j) {
        const int src = (k0 + j) * HID + n;
        vals[j] = w1bf ? W1u[src] : f2bf(W1f[src]);
    }
    unsigned short* dst = outp + (size_t)t * 65536 + (size_t)tid * 8;
    *reinterpret_cast<uint4*>(dst) = *reinterpret_cast<const uint4*>(vals);
}

// ---- main: software-pipelined gather + MFMA (bf16 tables) ----
extern "C" __global__ __launch_bounds__(256, 3)
void edge_mlp_bf16(
    const unsigned short* __restrict__ uT, const unsigned short* __restrict__ iT,
    const int* __restrict__ u0, const int* __restrict__ v0,
    const int* __restrict__ u1, const int* __restrict__ v1,
    const unsigned short* __restrict__ packedW1,
    const float* __restrict__ b1_0, const float* __restrict__ w2_0, const float* __restrict__ b2_0,
    const float* __restrict__ b1_1, const float* __restrict__ w2_1, const float* __restrict__ b2_1,
    float* __restrict__ out, int E, int nTiles)
{
    __shared__ unsigned short sA[64 * LDS_US];   // 33 KB: [64 edges][256 k] bf16
    __shared__ float pRed[4][64];

    const int t = blockIdx.y;
    const int* uI = t ? u1 : u0;
    const int* vI = t ? v1 : v0;
    const float* b1 = t ? b1_1 : b1_0;
    const float* w2 = t ? w2_1 : w2_0;
    const float b2v = t ? b2_1[0] : b2_0[0];
    const unsigned short* pW = packedW1 + (size_t)t * 65536;

    const int tid  = threadIdx.x;
    const int el   = tid >> 3;      // gather: 32 edges/pass, 2 passes, 8 threads/edge
    const int o    = tid & 7;
    const int wv   = tid >> 6;      // wave owns n-tiles wv*4..wv*4+3
    const int lane = tid & 63;
    const int lq   = lane >> 4;
    const int lm   = lane & 15;
    const int tile0 = blockIdx.x * TPB;

    uint4 pf[8];          // prefetched rows: [pass p][chunk i] = pf[p*4+i]
    int iuN[2], ivN[2];   // indices for tile+1 (prefetched one tile ahead)

    // prologue: idx+rows(tile0), idx(tile0+1)
    {
        int iu[2], iv[2];
#pragma unroll
        for (int p = 0; p < 2; ++p) {
            int e = tile0 * 64 + p * 32 + el;
            iu[p] = (e < E) ? uI[e] : 0;
            iv[p] = (e < E) ? vI[e] : 0;
        }
#pragma unroll
        for (int p = 0; p < 2; ++p) {
            int e = tile0 * 64 + p * 32 + el;
            if (e < E) {
                const uint4* ru = reinterpret_cast<const uint4*>(uT + (size_t)iu[p] * IN_DIM);
                const uint4* rv = reinterpret_cast<const uint4*>(iT + (size_t)iv[p] * IN_DIM);
                pf[p*4+0] = ru[o];   pf[p*4+1] = ru[o+8];
                pf[p*4+2] = rv[o];   pf[p*4+3] = rv[o+8];
            } else {
                uint4 z; z.x = z.y = z.z = z.w = 0;
                pf[p*4+0] = z; pf[p*4+1] = z; pf[p*4+2] = z; pf[p*4+3] = z;
            }
        }
#pragma unroll
        for (int p = 0; p < 2; ++p) {
            int e = (tile0 + 1) * 64 + p * 32 + el;
            iuN[p] = (e < E) ? uI[e] : 0;
            ivN[p] = (e < E) ? vI[e] : 0;
        }
    }

    for (int j = 0; j < TPB; ++j) {
        const int tile = tile0 + j;
        if (tile >= nTiles) break;    // block-uniform

        __syncthreads();              // prev iter's LDS readers done
        // commit pf -> sA. banks: (4*el + 4*(o+8i)) % 32 = 4*(el+o)%32 -> conflict-free phases
#pragma unroll
        for (int p = 0; p < 2; ++p) {
            uint4* d4 = reinterpret_cast<uint4*>(&sA[(p * 32 + el) * LDS_US]);
            d4[o]      = pf[p*4+0];
            d4[o + 8]  = pf[p*4+1];
            d4[o + 16] = pf[p*4+2];
            d4[o + 24] = pf[p*4+3];
        }
        __syncthreads();

        // prefetch next tile's rows (latency hidden behind K-loop below)
        if (j + 1 < TPB) {
#pragma unroll
            for (int p = 0; p < 2; ++p) {
                int e = (tile + 1) * 64 + p * 32 + el;
                if (e < E) {
                    const uint4* ru = reinterpret_cast<const uint4*>(uT + (size_t)iuN[p] * IN_DIM);
                    const uint4* rv = reinterpret_cast<const uint4*>(iT + (size_t)ivN[p] * IN_DIM);
                    pf[p*4+0] = ru[o];   pf[p*4+1] = ru[o+8];
                    pf[p*4+2] = rv[o];   pf[p*4+3] = rv[o+8];
                } else {
                    uint4 z; z.x = z.y = z.z = z.w = 0;
                    pf[p*4+0] = z; pf[p*4+1] = z; pf[p*4+2] = z; pf[p*4+3] = z;
                }
            }
            if (j + 2 < TPB) {
#pragma unroll
                for (int p = 0; p < 2; ++p) {
                    int e = (tile + 2) * 64 + p * 32 + el;
                    iuN[p] = (e < E) ? uI[e] : 0;
                    ivN[p] = (e < E) ? vI[e] : 0;
                }
            }
        }

        // ---- K-loop ----
        f32x4 acc[4][4];
#pragma unroll
        for (int ms = 0; ms < 4; ++ms)
#pragma unroll
            for (int ntg = 0; ntg < 4; ++ntg)
                acc[ms][ntg] = (f32x4){0.f, 0.f, 0.f, 0.f};

#pragma unroll
        for (int kt = 0; kt < 8; ++kt) {
            const int koff = kt * 32 + lq * 8;
            bf16x8 aF[4];
#pragma unroll
            for (int ms = 0; ms < 4; ++ms)
                aF[ms] = *reinterpret_cast<const bf16x8*>(&sA[(ms * 16 + lm) * LDS_US + koff]);
#pragma unroll
            for (int ntg = 0; ntg < 4; ++ntg) {
                const int nt = wv * 4 + ntg;
                bf16x8 bF = *reinterpret_cast<const bf16x8*>(
                    pW + (((size_t)(kt * 16 + nt) * 64 + lane) * 8));
#pragma unroll
                for (int ms = 0; ms < 4; ++ms)
                    acc[ms][ntg] = __builtin_amdgcn_mfma_f32_16x16x32_bf16(aF[ms], bF, acc[ms][ntg], 0, 0, 0);
            }
        }

        // ---- epilogue: relu(acc+b1).w2, shuffle-reduce, store ----
        float part[4][4];
#pragma unroll
        for (int ms = 0; ms < 4; ++ms)
#pragma unroll
            for (int r = 0; r < 4; ++r) part[ms][r] = 0.f;

#pragma unroll
        for (int ntg = 0; ntg < 4; ++ntg) {
            const int n = (wv * 4 + ntg) * 16 + lm;
            const float b1n = b1[n];
            const float w2n = w2[n];
#pragma unroll
            for (int ms = 0; ms < 4; ++ms)
#pragma unroll
                for (int r = 0; r < 4; ++r) {
                    float h = fmaxf(acc[ms][ntg][r] + b1n, 0.f);
                    part[ms][r] = fmaf(h, w2n, part[ms][r]);
                }
        }
#pragma unroll
        for (int off = 1; off < 16; off <<= 1)
#pragma unroll
            for (int ms = 0; ms < 4; ++ms)
#pragma unroll
                for (int r = 0; r < 4; ++r)
                    part[ms][r] += __shfl_xor(part[ms][r], off, 64);

        if (lm == 0)
#pragma unroll
            for (int ms = 0; ms < 4; ++ms)
#pragma unroll
                for (int r = 0; r < 4; ++r)
                    pRed[wv][ms * 16 + lq * 4 + r] = part[ms][r];
        __syncthreads();

        if (tid < 64) {
            const int e = tile * 64 + tid;
            if (e < E) {
                float s = b2v + pRed[0][tid] + pRed[1][tid] + pRed[2][tid] + pRed[3][tid];
                out[(size_t)t * E + e] = s;
            }
        }
    }
}

// ---- fallback (proven R5 kernel): fp32 gather, unpipelined ----
extern "C" __global__ __launch_bounds__(256, 3)
void edge_mlp_f32(
    const void* __restrict__ user_embed, const void* __restrict__ item_embed,
    const int* __restrict__ u0, const int* __restrict__ v0,
    const int* __restrict__ u1, const int* __restrict__ v1,
    const unsigned short* __restrict__ packedW1,
    const void* __restrict__ b1_0, const void* __restrict__ w2_0, const void* __restrict__ b2_0,
    const void* __restrict__ b1_1, const void* __restrict__ w2_1, const void* __restrict__ b2_1,
    float* __restrict__ out, int E)
{
    __shared__ unsigned short sA[64 * LDS_US];
    __shared__ float pRed[4][64];
    const int t  = blockIdx.y;
    const int e0 = blockIdx.x * 64;
    const int tid = threadIdx.x;
    const int* uI = t ? u1 : u0;
    const int* vI = t ? v1 : v0;
    const void* b1 = t ? b1_1 : b1_0;
    const void* w2 = t ? w2_1 : w2_0;
    const void* b2 = t ? b2_1 : b2_0;
    const unsigned short* pW = packedW1 + (size_t)t * 65536;
    const bool uBf  = detect_bf16((const unsigned short*)user_embed, 1024);
    const bool iBf  = detect_bf16((const unsigned short*)item_embed, 1024);
    const bool w2Bf = detect_bf16((const unsigned short*)w2, 2);
    const bool u64f = detect_idx64(uI);
    const bool v64f = detect_idx64(vI);
    {
        const int el = tid >> 2;
        const int q  = tid & 3;
        const int e  = e0 + el;
        uint4* dst = reinterpret_cast<uint4*>(&sA[el * LDS_US + q * 64]);
        if (e < E) {
            size_t idx; const void* tab; bool tbf; int off;
            if (q < 2) { idx = (size_t)(u64f ? uI[2*e] : uI[e]); tab = user_embed; tbf = uBf; off = q * 64; }
            else       { idx = (size_t)(v64f ? vI[2*e] : vI[e]); tab = item_embed; tbf = iBf; off = (q-2) * 64; }
            if (tbf) {
                const uint4* s4 = reinterpret_cast<const uint4*>((const unsigned short*)tab + idx * IN_DIM + off);
#pragma unroll
                for (int i = 0; i < 8; ++i) dst[i] = s4[i];
            } else {
                const float4* s4 = reinterpret_cast<const float4*>((const float*)tab + idx * IN_DIM + off);
#pragma unroll
                for (int i = 0; i < 8; ++i) {
                    float4 f0 = s4[2*i], f1 = s4[2*i+1];
                    uint4 ov;
                    ov.x = pack2(f0.x, f0.y); ov.y = pack2(f0.z, f0.w);
                    ov.z = pack2(f1.x, f1.y); ov.w = pack2(f1.z, f1.w);
                    dst[i] = ov;
                }
            }
        } else {
            uint4 z; z.x = z.y = z.z = z.w = 0;
#pragma unroll
            for (int i = 0; i < 8; ++i) dst[i] = z;
        }
    }
    __syncthreads();
    const int wv = tid >> 6, lane = tid & 63, lq = lane >> 4, lm = lane & 15;
    f32x4 acc[4][4];
#pragma unroll
    for (int ms = 0; ms < 4; ++ms)
#pragma unroll
        for (int ntg = 0; ntg < 4; ++ntg) acc[ms][ntg] = (f32x4){0.f,0.f,0.f,0.f};
#pragma unroll
    for (int kt = 0; kt < 8; ++kt) {
        const int koff = kt * 32 + lq * 8;
        bf16x8 aF[4];
#pragma unroll
        for (int ms = 0; ms < 4; ++ms)
            aF[ms] = *reinterpret_cast<const bf16x8*>(&sA[(ms*16+lm) * LDS_US + koff]);
#pragma unroll
        for (int ntg = 0; ntg < 4; ++ntg) {
            const int nt = wv * 4 + ntg;
            bf16x8 bF = *reinterpret_cast<const bf16x8*>(pW + (((size_t)(kt*16+nt)*64 + lane)*8));
#pragma unroll
            for (int ms = 0; ms < 4; ++ms)
                acc[ms][ntg] = __builtin_amdgcn_mfma_f32_16x16x32_bf16(aF[ms], bF, acc[ms][ntg], 0, 0, 0);
        }
    }
    float part[4][4];
#pragma unroll
    for (int ms = 0; ms < 4; ++ms)
#pragma unroll
        for (int r = 0; r < 4; ++r) part[ms][r] = 0.f;
#pragma unroll
    for (int ntg = 0; ntg < 4; ++ntg) {
        const int n = (wv*4+ntg)*16 + lm;
        const float b1n = w2Bf ? bf2f(((const unsigned short*)b1)[n]) : ((const float*)b1)[n];
        const float w2n = w2Bf ? bf2f(((const unsigned short*)w2)[n]) : ((const float*)w2)[n];
#pragma unroll
        for (int ms = 0; ms < 4; ++ms)
#pragma unroll
            for (int r = 0; r < 4; ++r) {
                float h = fmaxf(acc[ms][ntg][r] + b1n, 0.f);
                part[ms][r] = fmaf(h, w2n, part[ms][r]);
            }
    }
#pragma unroll
    for (int off = 1; off < 16; off <<= 1)
#pragma unroll
        for (int ms = 0; ms < 4; ++ms)
#pragma unroll
            for (int r = 0; r < 4; ++r)
                part[ms][r] += __shfl_xor(part[ms][r], off, 64);
    if (lm == 0)
#pragma unroll
        for (int ms = 0; ms < 4; ++ms)
#pragma unroll
            for (int r = 0; r < 4; ++r)
                pRed[wv][ms*16 + lq*4 + r] = part[ms][r];
    __syncthreads();
    if (tid < 64) {
        const int e = e0 + tid;
        if (e < E) {
            const float b2v = w2Bf ? bf2f(((const unsigned short*)b2)[0]) : ((const float*)b2)[0];
            out[(size_t)t * E + e] = b2v + pRed[0][tid] + pRed[1][tid] + pRed[2][tid] + pRed[3][tid];
        }
    }
}

extern "C" void kernel_launch(void* const* d_in, const int* in_sizes, int n_in,
                              void* d_out, int out_size, void* d_ws, size_t ws_size,
                              hipStream_t stream)
{
    const void* user_embed = d_in[0];
    const void* item_embed = d_in[1];
    const int* u0 = (const int*)d_in[2];
    const int* v0 = (const int*)d_in[3];
    const int* u1 = (const int*)d_in[4];
    const int* v1 = (const int*)d_in[5];
    const void* W1c = d_in[6];
    const void* b1c = d_in[7];
    const void* w2c = d_in[8];
    const void* b2c = d_in[9];
    const void* W1b = d_in[10];
    const void* b1b = d_in[11];
    const void* w2b = d_in[12];
    const void* b2b = d_in[13];

    const int E = in_sizes[2];
    const size_t NU = (size_t)in_sizes[0];
    const size_t NI = (size_t)in_sizes[1];
    unsigned short* packedW1 = (unsigned short*)d_ws;          // 256 KB
    const size_t need = 262144 + 2 * (NU + NI);                // + bf16 tables (~77 MB)

    hipLaunchKernelGGL(pack_w1_kernel, dim3(32, 2), dim3(256), 0, stream, W1c, W1b, packedW1);

    const int nTiles = (E + 63) / 64;

    if (ws_size >= need) {
        unsigned short* ub = (unsigned short*)((char*)d_ws + 262144);
        unsigned short* ib = ub + NU;
        const int nu8 = (int)(NU / 8), ni8 = (int)(NI / 8);
        const int tot = nu8 + ni8;
        hipLaunchKernelGGL(cvt_tables_kernel, dim3((tot + 255) / 256), dim3(256), 0, stream,
                           (const float*)user_embed, (const float*)item_embed, ub, ib, nu8, ni8);
        dim3 grid((nTiles + TPB - 1) / TPB, 2);
        hipLaunchKernelGGL(edge_mlp_bf16, grid, dim3(256), 0, stream,
                           ub, ib, u0, v0, u1, v1, packedW1,
                           (const float*)b1c, (const float*)w2c, (const float*)b2c,
                           (const float*)b1b, (const float*)w2b, (const float*)b2b,
                           (float*)d_out, E, nTiles);
    } else {
        dim3 grid(nTiles, 2);
        hipLaunchKernelGGL(edge_mlp_f32, grid, dim3(256), 0, stream,
                           user_embed, item_embed, u0, v0, u1, v1, packedW1,
                           b1c, w2c, b2c, b1b, w2b, b2b,
                           (float*)d_out, E);
    }
}

// Round 7
// 462.385 us; speedup vs baseline: 1.4163x; 1.4163x over previous
//
#include <hip/hip_runtime.h>
#include <hip/hip_bf16.h>

typedef short bf16x8 __attribute__((ext_vector_type(8)));
typedef float f32x4 __attribute__((ext_vector_type(4)));

#define HID 256
#define IN_DIM 128
#define M_BLOCK 64
#define LDS_US 264   // ushorts; 132 dwords/row

__device__ __forceinline__ float bf2f(unsigned short x) {
    union { unsigned int u; float f; } c; c.u = ((unsigned int)x) << 16; return c.f;
}
__device__ __forceinline__ unsigned short f2bf(float f) {
    union { float f; unsigned int u; } c; c.f = f;
    unsigned int u = c.u;
    u += 0x7FFFu + ((u >> 16) & 1u);   // RNE
    return (unsigned short)(u >> 16);
}
__device__ __forceinline__ unsigned int pack2(float lo, float hi) {
    return (unsigned int)f2bf(lo) | ((unsigned int)f2bf(hi) << 16);
}
__device__ __forceinline__ bool detect_bf16(const unsigned short* p, int strideElems) {
    const int lane = threadIdx.x & 63;
    unsigned int u = p[(size_t)2 * lane * strideElems];
    unsigned int e = (u >> 7) & 0xFFu;
    bool bad = ((u & 0x7FFFu) != 0u) && (e < 90u || e > 141u);
    return __ballot(bad) == 0ull;
}
__device__ __forceinline__ bool detect_idx64(const int* p) {
    const int lane = threadIdx.x & 63;
    int v = p[2 * (lane * 64) + 1];
    return __ballot(v != 0) == 0ull;
}

// ---- prep 1: fp32 tables -> bf16 tables in d_ws (streaming, HBM-bound) ----
extern "C" __global__ void cvt_tables_kernel(
    const float* __restrict__ uT, const float* __restrict__ iT,
    unsigned short* __restrict__ ub, unsigned short* __restrict__ ib,
    int nu8, int ni8)
{
    int g = blockIdx.x * 256 + threadIdx.x;
    if (g >= nu8 + ni8) return;
    const float* src; unsigned short* dst; int idx;
    if (g < nu8) { src = uT; dst = ub; idx = g; }
    else         { src = iT; dst = ib; idx = g - nu8; }
    const float4* s4 = reinterpret_cast<const float4*>(src) + (size_t)idx * 2;
    float4 a = s4[0], b = s4[1];
    uint4 o;
    o.x = pack2(a.x, a.y); o.y = pack2(a.z, a.w);
    o.z = pack2(b.x, b.y); o.w = pack2(b.z, b.w);
    reinterpret_cast<uint4*>(dst)[idx] = o;
}

// ---- prep 2: W1 -> bf16 B-fragment order (proven) ----
extern "C" __global__ void pack_w1_kernel(
    const void* __restrict__ W1c, const void* __restrict__ W1b,
    unsigned short* __restrict__ outp)
{
    const int t = blockIdx.y;
    const void* W1 = t ? W1b : W1c;
    const unsigned short* W1u = (const unsigned short*)W1;
    const float* W1f = (const float*)W1;
    const bool w1bf = detect_bf16(W1u, 512);
    const int tid = blockIdx.x * 256 + threadIdx.x;
    const int lane = tid & 63;
    const int nt = (tid >> 6) & 15;
    const int kt = tid >> 10;
    const int k0 = kt * 32 + (lane >> 4) * 8;
    const int n  = nt * 16 + (lane & 15);
    unsigned short vals[8];
#pragma unroll
    for (int j = 0; j < 8; ++j) {
        const int src = (k0 + j) * HID + n;
        vals[j] = w1bf ? W1u[src] : f2bf(W1f[src]);
    }
    unsigned short* dst = outp + (size_t)t * 65536 + (size_t)tid * 8;
    *reinterpret_cast<uint4*>(dst) = *reinterpret_cast<const uint4*>(vals);
}

// ---- main: R5 structure verbatim, gather reads bf16 tables ----
extern "C" __global__ __launch_bounds__(256, 3)
void edge_mlp_bf16tab(
    const unsigned short* __restrict__ uT, const unsigned short* __restrict__ iT,
    const int* __restrict__ u0, const int* __restrict__ v0,
    const int* __restrict__ u1, const int* __restrict__ v1,
    const unsigned short* __restrict__ packedW1,
    const float* __restrict__ b1_0, const float* __restrict__ w2_0, const float* __restrict__ b2_0,
    const float* __restrict__ b1_1, const float* __restrict__ w2_1, const float* __restrict__ b2_1,
    float* __restrict__ out, int E)
{
    __shared__ unsigned short sA[M_BLOCK * LDS_US];
    __shared__ float pRed[4][M_BLOCK];

    const int t  = blockIdx.y;
    const int e0 = blockIdx.x * M_BLOCK;
    const int tid = threadIdx.x;

    const int* uI = t ? u1 : u0;
    const int* vI = t ? v1 : v0;
    const float* b1 = t ? b1_1 : b1_0;
    const float* w2 = t ? w2_1 : w2_0;
    const float b2v = t ? b2_1[0] : b2_0[0];
    const unsigned short* pW = packedW1 + (size_t)t * 65536;

    // gather: 4 threads/edge, each copies 64 ushorts (128 B) = 8 x uint4
    {
        const int el = tid >> 2;
        const int q  = tid & 3;          // quarter of concat row: k in [64q, 64q+64)
        const int e  = e0 + el;
        uint4* dst = reinterpret_cast<uint4*>(&sA[el * LDS_US + q * 64]);
        if (e < E) {
            const unsigned short* src = (q < 2)
                ? uT + (size_t)uI[e] * IN_DIM + q * 64
                : iT + (size_t)vI[e] * IN_DIM + (q - 2) * 64;
            const uint4* s4 = reinterpret_cast<const uint4*>(src);
#pragma unroll
            for (int i = 0; i < 8; ++i) dst[i] = s4[i];
        } else {
            uint4 z; z.x = z.y = z.z = z.w = 0;
#pragma unroll
            for (int i = 0; i < 8; ++i) dst[i] = z;
        }
    }
    __syncthreads();

    const int wv = tid >> 6, lane = tid & 63, lq = lane >> 4, lm = lane & 15;

    f32x4 acc[4][4];
#pragma unroll
    for (int ms = 0; ms < 4; ++ms)
#pragma unroll
        for (int ntg = 0; ntg < 4; ++ntg) acc[ms][ntg] = (f32x4){0.f,0.f,0.f,0.f};

#pragma unroll
    for (int kt = 0; kt < 8; ++kt) {
        const int koff = kt * 32 + lq * 8;
        bf16x8 aF[4];
#pragma unroll
        for (int ms = 0; ms < 4; ++ms)
            aF[ms] = *reinterpret_cast<const bf16x8*>(&sA[(ms * 16 + lm) * LDS_US + koff]);
#pragma unroll
        for (int ntg = 0; ntg < 4; ++ntg) {
            const int nt = wv * 4 + ntg;
            bf16x8 bF = *reinterpret_cast<const bf16x8*>(
                pW + (((size_t)(kt * 16 + nt) * 64 + lane) * 8));
#pragma unroll
            for (int ms = 0; ms < 4; ++ms)
                acc[ms][ntg] = __builtin_amdgcn_mfma_f32_16x16x32_bf16(aF[ms], bF, acc[ms][ntg], 0, 0, 0);
        }
    }

    float part[4][4];
#pragma unroll
    for (int ms = 0; ms < 4; ++ms)
#pragma unroll
        for (int r = 0; r < 4; ++r) part[ms][r] = 0.f;

#pragma unroll
    for (int ntg = 0; ntg < 4; ++ntg) {
        const int n = (wv * 4 + ntg) * 16 + lm;
        const float b1n = b1[n];
        const float w2n = w2[n];
#pragma unroll
        for (int ms = 0; ms < 4; ++ms)
#pragma unroll
            for (int r = 0; r < 4; ++r) {
                float h = fmaxf(acc[ms][ntg][r] + b1n, 0.f);
                part[ms][r] = fmaf(h, w2n, part[ms][r]);
            }
    }
#pragma unroll
    for (int off = 1; off < 16; off <<= 1)
#pragma unroll
        for (int ms = 0; ms < 4; ++ms)
#pragma unroll
            for (int r = 0; r < 4; ++r)
                part[ms][r] += __shfl_xor(part[ms][r], off, 64);

    if (lm == 0)
#pragma unroll
        for (int ms = 0; ms < 4; ++ms)
#pragma unroll
            for (int r = 0; r < 4; ++r)
                pRed[wv][ms * 16 + lq * 4 + r] = part[ms][r];
    __syncthreads();

    if (tid < M_BLOCK) {
        const int e = e0 + tid;
        if (e < E)
            out[(size_t)t * E + e] = b2v + pRed[0][tid] + pRed[1][tid] + pRed[2][tid] + pRed[3][tid];
    }
}

// ---- fallback (proven R5 kernel): fp32 gather, used if ws too small ----
extern "C" __global__ __launch_bounds__(256, 3)
void edge_mlp_f32(
    const void* __restrict__ user_embed, const void* __restrict__ item_embed,
    const int* __restrict__ u0, const int* __restrict__ v0,
    const int* __restrict__ u1, const int* __restrict__ v1,
    const unsigned short* __restrict__ packedW1,
    const void* __restrict__ b1_0, const void* __restrict__ w2_0, const void* __restrict__ b2_0,
    const void* __restrict__ b1_1, const void* __restrict__ w2_1, const void* __restrict__ b2_1,
    float* __restrict__ out, int E)
{
    __shared__ unsigned short sA[M_BLOCK * LDS_US];
    __shared__ float pRed[4][M_BLOCK];
    const int t  = blockIdx.y;
    const int e0 = blockIdx.x * M_BLOCK;
    const int tid = threadIdx.x;
    const int* uI = t ? u1 : u0;
    const int* vI = t ? v1 : v0;
    const void* b1 = t ? b1_1 : b1_0;
    const void* w2 = t ? w2_1 : w2_0;
    const void* b2 = t ? b2_1 : b2_0;
    const unsigned short* pW = packedW1 + (size_t)t * 65536;
    const bool uBf  = detect_bf16((const unsigned short*)user_embed, 1024);
    const bool iBf  = detect_bf16((const unsigned short*)item_embed, 1024);
    const bool w2Bf = detect_bf16((const unsigned short*)w2, 2);
    const bool u64f = detect_idx64(uI);
    const bool v64f = detect_idx64(vI);
    {
        const int el = tid >> 2;
        const int q  = tid & 3;
        const int e  = e0 + el;
        uint4* dst = reinterpret_cast<uint4*>(&sA[el * LDS_US + q * 64]);
        if (e < E) {
            size_t idx; const void* tab; bool tbf; int off;
            if (q < 2) { idx = (size_t)(u64f ? uI[2*e] : uI[e]); tab = user_embed; tbf = uBf; off = q * 64; }
            else       { idx = (size_t)(v64f ? vI[2*e] : vI[e]); tab = item_embed; tbf = iBf; off = (q-2) * 64; }
            if (tbf) {
                const uint4* s4 = reinterpret_cast<const uint4*>((const unsigned short*)tab + idx * IN_DIM + off);
#pragma unroll
                for (int i = 0; i < 8; ++i) dst[i] = s4[i];
            } else {
                const float4* s4 = reinterpret_cast<const float4*>((const float*)tab + idx * IN_DIM + off);
#pragma unroll
                for (int i = 0; i < 8; ++i) {
                    float4 f0 = s4[2*i], f1 = s4[2*i+1];
                    uint4 ov;
                    ov.x = pack2(f0.x, f0.y); ov.y = pack2(f0.z, f0.w);
                    ov.z = pack2(f1.x, f1.y); ov.w = pack2(f1.z, f1.w);
                    dst[i] = ov;
                }
            }
        } else {
            uint4 z; z.x = z.y = z.z = z.w = 0;
#pragma unroll
            for (int i = 0; i < 8; ++i) dst[i] = z;
        }
    }
    __syncthreads();
    const int wv = tid >> 6, lane = tid & 63, lq = lane >> 4, lm = lane & 15;
    f32x4 acc[4][4];
#pragma unroll
    for (int ms = 0; ms < 4; ++ms)
#pragma unroll
        for (int ntg = 0; ntg < 4; ++ntg) acc[ms][ntg] = (f32x4){0.f,0.f,0.f,0.f};
#pragma unroll
    for (int kt = 0; kt < 8; ++kt) {
        const int koff = kt * 32 + lq * 8;
        bf16x8 aF[4];
#pragma unroll
        for (int ms = 0; ms < 4; ++ms)
            aF[ms] = *reinterpret_cast<const bf16x8*>(&sA[(ms*16+lm) * LDS_US + koff]);
#pragma unroll
        for (int ntg = 0; ntg < 4; ++ntg) {
            const int nt = wv * 4 + ntg;
            bf16x8 bF = *reinterpret_cast<const bf16x8*>(pW + (((size_t)(kt*16+nt)*64 + lane)*8));
#pragma unroll
            for (int ms = 0; ms < 4; ++ms)
                acc[ms][ntg] = __builtin_amdgcn_mfma_f32_16x16x32_bf16(aF[ms], bF, acc[ms][ntg], 0, 0, 0);
        }
    }
    float part[4][4];
#pragma unroll
    for (int ms = 0; ms < 4; ++ms)
#pragma unroll
        for (int r = 0; r < 4; ++r) part[ms][r] = 0.f;
#pragma unroll
    for (int ntg = 0; ntg < 4; ++ntg) {
        const int n = (wv*4+ntg)*16 + lm;
        const float b1n = w2Bf ? bf2f(((const unsigned short*)b1)[n]) : ((const float*)b1)[n];
        const float w2n = w2Bf ? bf2f(((const unsigned short*)w2)[n]) : ((const float*)w2)[n];
#pragma unroll
        for (int ms = 0; ms < 4; ++ms)
#pragma unroll
            for (int r = 0; r < 4; ++r) {
                float h = fmaxf(acc[ms][ntg][r] + b1n, 0.f);
                part[ms][r] = fmaf(h, w2n, part[ms][r]);
            }
    }
#pragma unroll
    for (int off = 1; off < 16; off <<= 1)
#pragma unroll
        for (int ms = 0; ms < 4; ++ms)
#pragma unroll
            for (int r = 0; r < 4; ++r)
                part[ms][r] += __shfl_xor(part[ms][r], off, 64);
    if (lm == 0)
#pragma unroll
        for (int ms = 0; ms < 4; ++ms)
#pragma unroll
            for (int r = 0; r < 4; ++r)
                pRed[wv][ms*16 + lq*4 + r] = part[ms][r];
    __syncthreads();
    if (tid < M_BLOCK) {
        const int e = e0 + tid;
        if (e < E) {
            const float b2v = w2Bf ? bf2f(((const unsigned short*)b2)[0]) : ((const float*)b2)[0];
            out[(size_t)t * E + e] = b2v + pRed[0][tid] + pRed[1][tid] + pRed[2][tid] + pRed[3][tid];
        }
    }
}

extern "C" void kernel_launch(void* const* d_in, const int* in_sizes, int n_in,
                              void* d_out, int out_size, void* d_ws, size_t ws_size,
                              hipStream_t stream)
{
    const void* user_embed = d_in[0];
    const void* item_embed = d_in[1];
    const int* u0 = (const int*)d_in[2];
    const int* v0 = (const int*)d_in[3];
    const int* u1 = (const int*)d_in[4];
    const int* v1 = (const int*)d_in[5];
    const void* W1c = d_in[6];
    const void* b1c = d_in[7];
    const void* w2c = d_in[8];
    const void* b2c = d_in[9];
    const void* W1b = d_in[10];
    const void* b1b = d_in[11];
    const void* w2b = d_in[12];
    const void* b2b = d_in[13];

    const int E = in_sizes[2];
    const size_t NU = (size_t)in_sizes[0];   // user table elems (100000*128)
    const size_t NI = (size_t)in_sizes[1];   // item table elems (200000*128)
    unsigned short* packedW1 = (unsigned short*)d_ws;          // 256 KB
    const size_t need = 262144 + 2 * (NU + NI);                // + bf16 tables (~77 MB)

    hipLaunchKernelGGL(pack_w1_kernel, dim3(32, 2), dim3(256), 0, stream, W1c, W1b, packedW1);

    dim3 grid((E + M_BLOCK - 1) / M_BLOCK, 2);

    if (ws_size >= need) {
        unsigned short* ub = (unsigned short*)((char*)d_ws + 262144);
        unsigned short* ib = ub + NU;
        const int nu8 = (int)(NU / 8), ni8 = (int)(NI / 8);
        const int tot = nu8 + ni8;
        hipLaunchKernelGGL(cvt_tables_kernel, dim3((tot + 255) / 256), dim3(256), 0, stream,
                           (const float*)user_embed, (const float*)item_embed, ub, ib, nu8, ni8);
        hipLaunchKernelGGL(edge_mlp_bf16tab, grid, dim3(256), 0, stream,
                           ub, ib, u0, v0, u1, v1, packedW1,
                           (const float*)b1c, (const float*)w2c, (const float*)b2c,
                           (const float*)b1b, (const float*)w2b, (const float*)b2b,
                           (float*)d_out, E);
    } else {
        hipLaunchKernelGGL(edge_mlp_f32, grid, dim3(256), 0, stream,
                           user_embed, item_embed, u0, v0, u1, v1, packedW1,
                           b1c, w2c, b2c, b1b, w2b, b2b,
                           (float*)d_out, E);
    }
}